// Round 3
// baseline (1578.489 us; speedup 1.0000x reference)
//
#include <hip/hip_runtime.h>

// GlobalFusion: merge(1x1 -> gelu -> dw3x3 -> gelu -> 1x1) + residual,
// 2x minGRU over V (flips over H cancel), softmax view pooling,
// 1x1 + pixel_shuffle(4) [resize is identity], 3x3 out conv.
// Round 3: inputs fp32 (confirmed R2); OUTPUT now fp32 (R2's 0.073 error matched
// the "bf16 packed into fp32 buffer" misplacement signature exactly).
// Internal compute fp32, intermediates bf16.

#define DEV static __device__ __forceinline__

constexpr int Bc = 2, Vc = 6, Cc = 128, Hc = 128, Wc = 128;
constexpr int Nc = Bc * Vc;      // 12
constexpr int Pc = Hc * Wc;      // 16384

DEV float us2f(unsigned short u) {
  return __builtin_bit_cast(float, (unsigned int)u << 16);
}
DEV unsigned short f2us(float f) {
  unsigned int i = __builtin_bit_cast(unsigned int, f);
  unsigned int r = i + 0x7FFFu + ((i >> 16) & 1u);   // RNE
  return (unsigned short)(r >> 16);
}
DEV float geluf(float x) { return x * 0.5f * (1.f + erff(x * 0.70710678118654752f)); }
DEV float sigm(float x) { return 1.f / (1.f + __expf(-x)); }

// dtype-agnostic input load: bf=1 -> bf16, bf=0 -> fp32
DEV float ldin(const void* p, size_t i, int bf) {
  if (bf) return us2f(((const unsigned short*)p)[i]);
  return ((const float*)p)[i];
}

// ---------------- detector: is input data bf16 or fp32 bytes? ----------------
__global__ void k_detect(const unsigned short* __restrict__ w, int* __restrict__ flag) {
  if (threadIdx.x == 0 && blockIdx.x == 0) {
    int big = 0;
    for (int i = 0; i < 2048; ++i) {
      unsigned e = (w[i] >> 7) & 0xFFu;   // bf16 exponent field
      if (e >= 0x86u) big++;              // |v| >= 64
    }
    flag[0] = (big > 64) ? 0 : 1;         // many huge -> fp32 bytes
  }
}

// ---------------- weight transpose: w[M][K] -> wt[K][M] (f32) ----------------
__global__ void k_transpose(const void* __restrict__ w, float* __restrict__ wt,
                            int M, int K, const int* __restrict__ dflag) {
  const int bf = dflag[0];
  int i = blockIdx.x * 256 + threadIdx.x;
  if (i >= M * K) return;
  int k = i % K, m = i / K;
  wt[(size_t)k * M + m] = ldin(w, i, bf);
}

// ---------------- K1: 1x1 conv 256->128 + GELU ----------------
constexpr int TO = 64, TP = 64, TK = 64;

__global__ __launch_bounds__(256) void k_merge1(
    const void* __restrict__ feats, const void* __restrict__ prj,
    const float* __restrict__ w1T, const void* __restrict__ b1,
    unsigned short* __restrict__ out, const int* __restrict__ dflag) {
  const int bf = dflag[0];
  __shared__ float At[TK][TO];
  __shared__ float Bt[TK][TP];
  const int n = blockIdx.z, o0 = blockIdx.y * TO, p0 = blockIdx.x * TP;
  const int t = threadIdx.x, tm = t >> 4, tn = t & 15;
  float acc[4][4] = {{0.f}};
  for (int k0 = 0; k0 < 2 * Cc; k0 += TK) {
    for (int i = t; i < TK * TO; i += 256) {
      int o = i & 63, k = i >> 6;
      At[k][o] = w1T[(size_t)(k0 + k) * Cc + o0 + o];
    }
    for (int i = t; i < TK * TP; i += 256) {
      int p = i & 63, k = i >> 6;
      int c = k0 + k;
      size_t idx = (c < Cc)
          ? ((size_t)n * Cc + c) * Pc + p0 + p
          : ((size_t)n * Cc + (c - Cc)) * Pc + p0 + p;
      Bt[k][p] = (c < Cc) ? ldin(feats, idx, bf) : ldin(prj, idx, bf);
    }
    __syncthreads();
    for (int k = 0; k < TK; ++k) {
      float4 a4 = *reinterpret_cast<const float4*>(&At[k][tm * 4]);
      float4 b4 = *reinterpret_cast<const float4*>(&Bt[k][tn * 4]);
      const float a[4] = {a4.x, a4.y, a4.z, a4.w};
      const float bb[4] = {b4.x, b4.y, b4.z, b4.w};
#pragma unroll
      for (int i = 0; i < 4; i++)
#pragma unroll
        for (int j = 0; j < 4; j++) acc[i][j] = fmaf(a[i], bb[j], acc[i][j]);
    }
    __syncthreads();
  }
#pragma unroll
  for (int i = 0; i < 4; i++) {
    int o = o0 + tm * 4 + i;
    float bias = ldin(b1, o, bf);
    ushort4 pk;
    pk.x = f2us(geluf(acc[i][0] + bias));
    pk.y = f2us(geluf(acc[i][1] + bias));
    pk.z = f2us(geluf(acc[i][2] + bias));
    pk.w = f2us(geluf(acc[i][3] + bias));
    *reinterpret_cast<ushort4*>(out + ((size_t)n * Cc + o) * Pc + p0 + tn * 4) = pk;
  }
}

// ---------------- K2: depthwise 3x3 + GELU ----------------
__global__ __launch_bounds__(256) void k_dw(
    const unsigned short* __restrict__ in, const void* __restrict__ wd,
    const void* __restrict__ bd, unsigned short* __restrict__ out,
    const int* __restrict__ dflag) {
  const int bf = dflag[0];
  const int idx = blockIdx.x * 256 + threadIdx.x;   // over N*C*P
  const int p = idx & (Pc - 1);
  const int nc = idx >> 14;
  const int c = nc & (Cc - 1);
  const int y = p >> 7, x = p & 127;
  const unsigned short* plane = in + (size_t)nc * Pc;
  float wv[9];
#pragma unroll
  for (int i = 0; i < 9; i++) wv[i] = ldin(wd, c * 9 + i, bf);
  float acc = ldin(bd, c, bf);
#pragma unroll
  for (int dy = 0; dy < 3; ++dy) {
    int yy = y + dy - 1;
    if (yy < 0 || yy >= Hc) continue;
#pragma unroll
    for (int dx = 0; dx < 3; ++dx) {
      int xx = x + dx - 1;
      if (xx < 0 || xx >= Wc) continue;
      acc += wv[dy * 3 + dx] * us2f(plane[yy * Wc + xx]);
    }
  }
  out[(size_t)nc * Pc + p] = f2us(geluf(acc));
}

// ---------------- K3: 1x1 conv 128->128 + bias + residual(feats) ----------------
__global__ __launch_bounds__(256) void k_merge2(
    const unsigned short* __restrict__ m2, const void* __restrict__ feats,
    const float* __restrict__ w2T, const void* __restrict__ b2,
    unsigned short* __restrict__ out, const int* __restrict__ dflag) {
  const int bf = dflag[0];
  __shared__ float At[TK][TO];
  __shared__ float Bt[TK][TP];
  const int n = blockIdx.z, o0 = blockIdx.y * TO, p0 = blockIdx.x * TP;
  const int t = threadIdx.x, tm = t >> 4, tn = t & 15;
  float acc[4][4] = {{0.f}};
  const unsigned short* ib = m2 + (size_t)n * Cc * Pc;
  for (int k0 = 0; k0 < Cc; k0 += TK) {
    for (int i = t; i < TK * TO; i += 256) {
      int o = i & 63, k = i >> 6;
      At[k][o] = w2T[(size_t)(k0 + k) * Cc + o0 + o];
    }
    for (int i = t; i < TK * TP; i += 256) {
      int p = i & 63, k = i >> 6;
      Bt[k][p] = us2f(ib[(size_t)(k0 + k) * Pc + p0 + p]);
    }
    __syncthreads();
    for (int k = 0; k < TK; ++k) {
      float4 a4 = *reinterpret_cast<const float4*>(&At[k][tm * 4]);
      float4 b4 = *reinterpret_cast<const float4*>(&Bt[k][tn * 4]);
      const float a[4] = {a4.x, a4.y, a4.z, a4.w};
      const float bb[4] = {b4.x, b4.y, b4.z, b4.w};
#pragma unroll
      for (int i = 0; i < 4; i++)
#pragma unroll
        for (int j = 0; j < 4; j++) acc[i][j] = fmaf(a[i], bb[j], acc[i][j]);
    }
    __syncthreads();
  }
#pragma unroll
  for (int i = 0; i < 4; i++) {
    int o = o0 + tm * 4 + i;
    float bias = ldin(b2, o, bf);
    ushort4 pk;
#pragma unroll
    for (int j = 0; j < 4; j++) {
      size_t ridx = ((size_t)n * Cc + o) * Pc + p0 + tn * 4 + j;
      float r = ldin(feats, ridx, bf);
      float v = acc[i][j] + bias + r;
      ((unsigned short*)&pk)[j] = f2us(v);
    }
    *reinterpret_cast<ushort4*>(out + ((size_t)n * Cc + o) * Pc + p0 + tn * 4) = pk;
  }
}

// ---------------- K4: fused minGRU (GEMM over C + scan over V) ----------------
constexpr int G_D = 32, G_P = 32, G_M = 64, G_N = Vc * G_P /*192*/, G_K = 32;

__global__ __launch_bounds__(256) void k_gru(
    const unsigned short* __restrict__ X, const float* __restrict__ WT,
    unsigned short* __restrict__ Hout) {
  __shared__ union {
    struct { float A[G_K][G_M]; float B[G_K][G_N]; } s;   // 32 KB
    float hg[G_M][G_N];                                   // 48 KB
  } L;
  const int b = blockIdx.z;
  const int d0 = blockIdx.y * G_D;
  const int p0 = blockIdx.x * G_P;
  const int t = threadIdx.x, tm = t >> 4, tn = t & 15;
  float acc[4][12];
#pragma unroll
  for (int i = 0; i < 4; i++)
#pragma unroll
    for (int j = 0; j < 12; j++) acc[i][j] = 0.f;

  for (int k0 = 0; k0 < Cc; k0 += G_K) {
    for (int i = t; i < G_K * G_M; i += 256) {
      int m = i & 63, kk = i >> 6;
      int row = (m < G_D) ? (d0 + m) : (Cc + d0 + (m - G_D));
      L.s.A[kk][m] = WT[(size_t)(k0 + kk) * 256 + row];
    }
    for (int i = t; i < G_K * G_N; i += 256) {
      int nn = i % G_N, kk = i / G_N;
      int v = nn >> 5, pp = nn & 31;
      L.s.B[kk][nn] = us2f(X[((size_t)(b * Vc + v) * Cc + (k0 + kk)) * Pc + p0 + pp]);
    }
    __syncthreads();
    for (int k = 0; k < G_K; ++k) {
      float4 a4 = *reinterpret_cast<const float4*>(&L.s.A[k][tm * 4]);
      float4 c0 = *reinterpret_cast<const float4*>(&L.s.B[k][tn * 12]);
      float4 c1 = *reinterpret_cast<const float4*>(&L.s.B[k][tn * 12 + 4]);
      float4 c2 = *reinterpret_cast<const float4*>(&L.s.B[k][tn * 12 + 8]);
      const float a[4] = {a4.x, a4.y, a4.z, a4.w};
      const float bb[12] = {c0.x, c0.y, c0.z, c0.w, c1.x, c1.y, c1.z, c1.w,
                            c2.x, c2.y, c2.z, c2.w};
#pragma unroll
      for (int i = 0; i < 4; i++)
#pragma unroll
        for (int j = 0; j < 12; j++) acc[i][j] = fmaf(a[i], bb[j], acc[i][j]);
    }
    __syncthreads();
  }
#pragma unroll
  for (int i = 0; i < 4; i++)
#pragma unroll
    for (int j = 0; j < 12; j++) L.hg[tm * 4 + i][tn * 12 + j] = acc[i][j];
  __syncthreads();
  // inclusive scan over V: h = (1-z)h + z*htilde; h_{-1}=0
  for (int q = t; q < G_D * G_P; q += 256) {
    int d = q >> 5, pp = q & 31;
    float h = 0.f;
#pragma unroll
    for (int v = 0; v < Vc; ++v) {
      float hid = L.hg[d][v * G_P + pp];
      float gat = L.hg[G_D + d][v * G_P + pp];
      float z = sigm(gat);
      float ht = (hid >= 0.f) ? (hid + 0.5f) : sigm(hid);
      h = (1.f - z) * h + z * ht;
      Hout[((size_t)(b * Vc + v) * Cc + (d0 + d)) * Pc + p0 + pp] = f2us(h);
    }
  }
}

// ---------------- K5: alpha = 3x3 conv (128 -> 1) ----------------
__global__ __launch_bounds__(256) void k_alpha(
    const unsigned short* __restrict__ F, const void* __restrict__ wa,
    const void* __restrict__ ba, float* __restrict__ alpha,
    const int* __restrict__ dflag) {
  const int bf = dflag[0];
  __shared__ float w[Cc * 9];
  for (int i = threadIdx.x; i < Cc * 9; i += 256) w[i] = ldin(wa, i, bf);
  __syncthreads();
  const int n = blockIdx.x >> 6;
  const int p = (blockIdx.x & 63) * 256 + threadIdx.x;
  const int y = p >> 7, x = p & 127;
  const unsigned short* base = F + (size_t)n * Cc * Pc;
  float acc = ldin(ba, 0, bf);
#pragma unroll
  for (int dy = 0; dy < 3; ++dy) {
    int yy = y + dy - 1;
    if (yy < 0 || yy >= Hc) continue;
#pragma unroll
    for (int dx = 0; dx < 3; ++dx) {
      int xx = x + dx - 1;
      if (xx < 0 || xx >= Wc) continue;
      const unsigned short* col = base + yy * Wc + xx;
      const float* wk = w + dy * 3 + dx;
      float s = 0.f;
      for (int c = 0; c < Cc; ++c) s += wk[c * 9] * us2f(col[(size_t)c * Pc]);
      acc += s;
    }
  }
  alpha[(size_t)n * Pc + p] = acc;
}

// ---------------- K6: softmax over V + weighted pool ----------------
__global__ __launch_bounds__(256) void k_pool(
    const unsigned short* __restrict__ F, const float* __restrict__ alpha,
    float* __restrict__ fp) {
  const int idx = blockIdx.x * 256 + threadIdx.x;   // over B*C*P
  const int p = idx & (Pc - 1);
  const int bc = idx >> 14;
  const int c = bc & (Cc - 1);
  const int b = bc >> 7;
  float av[Vc];
  float mx = -1e30f;
#pragma unroll
  for (int v = 0; v < Vc; ++v) {
    av[v] = alpha[(size_t)(b * Vc + v) * Pc + p];
    mx = fmaxf(mx, av[v]);
  }
  float s = 0.f;
#pragma unroll
  for (int v = 0; v < Vc; ++v) { av[v] = __expf(av[v] - mx); s += av[v]; }
  const float inv = 1.f / s;
  float acc = 0.f;
#pragma unroll
  for (int v = 0; v < Vc; ++v)
    acc += us2f(F[((size_t)(b * Vc + v) * Cc + c) * Pc + p]) * (av[v] * inv);
  fp[idx] = acc;
}

// ---------------- K7: 1x1 conv 128->128 + pixel_shuffle(4) ----------------
__global__ __launch_bounds__(256) void k_up(
    const float* __restrict__ fp, const float* __restrict__ wuT,
    const void* __restrict__ bu, unsigned short* __restrict__ us_,
    const int* __restrict__ dflag) {
  const int bf = dflag[0];
  __shared__ float At[TK][TO];
  __shared__ float Bt[TK][TP];
  const int b = blockIdx.z, o0 = blockIdx.y * TO, p0 = blockIdx.x * TP;
  const int t = threadIdx.x, tm = t >> 4, tn = t & 15;
  float acc[4][4] = {{0.f}};
  for (int k0 = 0; k0 < Cc; k0 += TK) {
    for (int i = t; i < TK * TO; i += 256) {
      int o = i & 63, k = i >> 6;
      At[k][o] = wuT[(size_t)(k0 + k) * Cc + o0 + o];
    }
    for (int i = t; i < TK * TP; i += 256) {
      int p = i & 63, k = i >> 6;
      Bt[k][p] = fp[((size_t)b * Cc + (k0 + k)) * Pc + p0 + p];
    }
    __syncthreads();
    for (int k = 0; k < TK; ++k) {
      float4 a4 = *reinterpret_cast<const float4*>(&At[k][tm * 4]);
      float4 b4 = *reinterpret_cast<const float4*>(&Bt[k][tn * 4]);
      const float a[4] = {a4.x, a4.y, a4.z, a4.w};
      const float bb[4] = {b4.x, b4.y, b4.z, b4.w};
#pragma unroll
      for (int i = 0; i < 4; i++)
#pragma unroll
        for (int j = 0; j < 4; j++) acc[i][j] = fmaf(a[i], bb[j], acc[i][j]);
    }
    __syncthreads();
  }
#pragma unroll
  for (int i = 0; i < 4; i++) {
    int cc = o0 + tm * 4 + i;
    float bias = ldin(bu, cc, bf);
    int co = cc >> 4, r1 = (cc >> 2) & 3, r2 = cc & 3;
#pragma unroll
    for (int j = 0; j < 4; j++) {
      int p = p0 + tn * 4 + j;
      int y = p >> 7, x = p & 127;
      us_[(((size_t)b * 8 + co) * 512 + (y * 4 + r1)) * 512 + (x * 4 + r2)] =
          f2us(acc[i][j] + bias);
    }
  }
}

// ---------------- K8: 3x3 conv 8->3 on 512x512, fp32 output ----------------
__global__ __launch_bounds__(256) void k_outc(
    const unsigned short* __restrict__ us_, const void* __restrict__ wo,
    const void* __restrict__ bo, float* __restrict__ out,
    const int* __restrict__ dflag) {
  const int bf = dflag[0];
  __shared__ float w[3 * 8 * 9];
  for (int i = threadIdx.x; i < 216; i += 256) w[i] = ldin(wo, i, bf);
  __syncthreads();
  int i = blockIdx.x;
  const int xh = i & 1; i >>= 1;
  const int Y = i & 511; i >>= 9;
  const int o = i % 3;
  const int b = i / 3;
  const int X = xh * 256 + threadIdx.x;
  float acc = ldin(bo, o, bf);
  for (int ci = 0; ci < 8; ++ci) {
    const unsigned short* pl = us_ + ((size_t)b * 8 + ci) * 512 * 512;
    const float* wc = w + o * 72 + ci * 9;
#pragma unroll
    for (int dy = 0; dy < 3; ++dy) {
      int YY = Y + dy - 1;
      if (YY < 0 || YY >= 512) continue;
#pragma unroll
      for (int dx = 0; dx < 3; ++dx) {
        int XX = X + dx - 1;
        if (XX < 0 || XX >= 512) continue;
        acc += wc[dy * 3 + dx] * us2f(pl[(size_t)YY * 512 + XX]);
      }
    }
  }
  out[(((size_t)b * 3 + o) * 512 + Y) * 512 + X] = acc;   // fp32 store
}

// ---------------- launcher ----------------
extern "C" void kernel_launch(void* const* d_in, const int* in_sizes, int n_in,
                              void* d_out, int out_size, void* d_ws, size_t ws_size,
                              hipStream_t stream) {
  const void* feats = d_in[0];
  const void* prj = d_in[1];
  const void* w1 = d_in[2];
  const void* b1 = d_in[3];
  const void* wd = d_in[4];
  const void* bd = d_in[5];
  const void* w2 = d_in[6];
  const void* b2 = d_in[7];
  const void* gw = d_in[8];
  const void* gbw = d_in[9];
  const void* wa = d_in[10];
  const void* ba = d_in[11];
  const void* wu = d_in[12];
  const void* bu = d_in[13];
  const void* wo = d_in[14];
  const void* bo = d_in[15];
  float* out = (float*)d_out;

  char* ws = (char*)d_ws;
  unsigned short* bufA = (unsigned short*)(ws + 0);            // 50,331,648
  unsigned short* bufB = (unsigned short*)(ws + 50331648);     // 50,331,648
  float* alpha = (float*)(ws + 100663296);                     // 786,432
  float* fpool = (float*)(ws + 101449728);                     // 16,777,216
  unsigned short* ushuf = (unsigned short*)(ws + 118226944);   // 8,388,608
  float* w1T = (float*)(ws + 126615552);                       // 131,072
  float* w2T = w1T + 256 * 128;                                // 65,536
  float* gwT = w2T + 128 * 128;                                // 131,072
  float* gbwT = gwT + 128 * 256;                               // 131,072
  float* wuT = gbwT + 128 * 256;                               // 65,536
  int* dflag = (int*)(ws + 127139840);                         // 4 bytes

  dim3 blk(256);
  k_detect<<<dim3(1), dim3(64), 0, stream>>>((const unsigned short*)w1, dflag);

  k_transpose<<<dim3(128), blk, 0, stream>>>(w1, w1T, 128, 256, dflag);
  k_transpose<<<dim3(64), blk, 0, stream>>>(w2, w2T, 128, 128, dflag);
  k_transpose<<<dim3(128), blk, 0, stream>>>(gw, gwT, 256, 128, dflag);
  k_transpose<<<dim3(128), blk, 0, stream>>>(gbw, gbwT, 256, 128, dflag);
  k_transpose<<<dim3(64), blk, 0, stream>>>(wu, wuT, 128, 128, dflag);

  k_merge1<<<dim3(Pc / TP, Cc / TO, Nc), blk, 0, stream>>>(feats, prj, w1T, b1, bufA, dflag);
  k_dw<<<dim3((Nc * Cc * Pc) / 256), blk, 0, stream>>>(bufA, wd, bd, bufB, dflag);
  k_merge2<<<dim3(Pc / TP, Cc / TO, Nc), blk, 0, stream>>>(bufB, feats, w2T, b2, bufA, dflag);
  k_gru<<<dim3(Pc / G_P, Cc / G_D, Bc), blk, 0, stream>>>(bufA, gwT, bufB);
  k_gru<<<dim3(Pc / G_P, Cc / G_D, Bc), blk, 0, stream>>>(bufB, gbwT, bufA);
  k_alpha<<<dim3(Nc * (Pc / 256)), blk, 0, stream>>>(bufA, wa, ba, alpha, dflag);
  k_pool<<<dim3((Bc * Cc * Pc) / 256), blk, 0, stream>>>(bufA, alpha, fpool);
  k_up<<<dim3(Pc / TP, Cc / TO, Bc), blk, 0, stream>>>(fpool, wuT, bu, ushuf, dflag);
  k_outc<<<dim3(2 * 3 * 512 * 2), blk, 0, stream>>>(ushuf, wo, bo, out, dflag);

  (void)in_sizes; (void)n_in; (void)out_size; (void)ws_size;
}

// Round 4
// 702.189 us; speedup vs baseline: 2.2480x; 2.2480x over previous
//
#include <hip/hip_runtime.h>

// GlobalFusion R4: bf16 MFMA for all GEMM-shaped stages.
// Activation layout: [pixel][channel] bf16 (channel-contiguous) so MFMA A/B
// fragments are contiguous 16B LDS reads. Weights [out][in] used directly.
// fp32 inputs/output (confirmed R3). Fused bidirectional minGRU in one kernel.

#define DEV static __device__ __forceinline__

typedef __attribute__((ext_vector_type(8))) short short8x;
typedef __attribute__((ext_vector_type(4))) float f32x4;

constexpr int Bc = 2, Vc = 6, Cc = 128, Hc = 128, Wc = 128;
constexpr int Nc = Bc * Vc;      // 12
constexpr int Pc = Hc * Wc;      // 16384
constexpr int NPX = Nc * Pc;     // 196608

DEV float us2f(unsigned short u) {
  return __builtin_bit_cast(float, (unsigned int)u << 16);
}
DEV unsigned short f2us(float f) {
  unsigned int i = __builtin_bit_cast(unsigned int, f);
  unsigned int r = i + 0x7FFFu + ((i >> 16) & 1u);   // RNE
  return (unsigned short)(r >> 16);
}
DEV float geluf(float x) { return x * 0.5f * (1.f + erff(x * 0.70710678118654752f)); }
DEV float sigm(float x) { return 1.f / (1.f + __expf(-x)); }

// ---------------- weight prep: fp32 -> bf16 (+ GRU row interleave) ----------------
// wbf layout: [0..32768) w1b [128][256]; [32768..49152) w2b [128][128];
// [49152..65536) wub [128][128]; [65536..98304) wgi [256][128] interleaved;
// [98304..131072) wgbi [256][128] interleaved.
// Interleave: dst row n' -> j=n'>>5, s=n'&31: src = s<16 ? 16j+s : 128+16j+(s-16).
__global__ __launch_bounds__(256) void k_prepw(
    const float* __restrict__ w1, const float* __restrict__ w2,
    const float* __restrict__ wu, const float* __restrict__ gw,
    const float* __restrict__ gbw, unsigned short* __restrict__ wbf) {
  int idx = blockIdx.x * 256 + threadIdx.x;
  float v;
  if (idx < 32768) {
    v = w1[idx];
  } else if (idx < 49152) {
    v = w2[idx - 32768];
  } else if (idx < 65536) {
    v = wu[idx - 49152];
  } else {
    int i = (idx < 98304) ? (idx - 65536) : (idx - 98304);
    int np = i >> 7, k = i & 127;
    int j = np >> 5, s = np & 31;
    int src = (s < 16) ? (16 * j + s) : (128 + 16 * j + (s - 16));
    const float* w = (idx < 98304) ? gw : gbw;
    v = w[src * 128 + k];
  }
  wbf[idx] = f2us(v);
}

// ---------------- K1: merge 1x1 conv 256->128 + GELU (MFMA) ----------------
// Also emits fres = bf16(feats) in [px][128] layout (slice copy from LDS).
__global__ __launch_bounds__(256) void k_merge1(
    const float* __restrict__ feats, const float* __restrict__ prj,
    const unsigned short* __restrict__ w1b, const float* __restrict__ b1,
    unsigned short* __restrict__ m1, unsigned short* __restrict__ fres) {
  __shared__ unsigned short sA[128][72];
  __shared__ unsigned short sB[128][72];
  const int t = threadIdx.x;
  const int wave = t >> 6, lane = t & 63, quad = lane >> 4, lr = lane & 15;
  const int wm = (wave >> 1) * 64, wn = (wave & 1) * 64;
  const int mb = blockIdx.x;
  const size_t m0 = (size_t)mb * 128;
  const int n = mb >> 7;
  const int p0 = (mb & 127) << 7;
  f32x4 acc[4][4];
#pragma unroll
  for (int i = 0; i < 4; i++)
#pragma unroll
    for (int j = 0; j < 4; j++) acc[i][j] = (f32x4){0.f, 0.f, 0.f, 0.f};

  for (int k0 = 0; k0 < 256; k0 += 64) {
    // stage A: transpose fp32 [c][p] -> bf16 LDS [px][c_local]
    for (int u = t; u < 8192; u += 256) {
      int px = u & 127, c = u >> 7;
      int ch = k0 + c;
      const float* src = (ch < 128)
          ? (feats + ((size_t)(n * 128 + ch)) * Pc)
          : (prj + ((size_t)(n * 128 + (ch - 128))) * Pc);
      sA[px][c] = f2us(src[p0 + px]);
    }
    // stage B: weights [128 out][256 in] slice
    for (int u = t; u < 1024; u += 256) {
      int row = u >> 3, seg = u & 7;
      *(uint4*)&sB[row][seg * 8] =
          *(const uint4*)(w1b + (size_t)row * 256 + k0 + seg * 8);
    }
    __syncthreads();
#pragma unroll
    for (int ks = 0; ks < 2; ++ks) {
      const int kk = ks * 32 + quad * 8;
      short8x a[4], bf[4];
#pragma unroll
      for (int i = 0; i < 4; i++)
        a[i] = *reinterpret_cast<const short8x*>(&sA[wm + i * 16 + lr][kk]);
#pragma unroll
      for (int j = 0; j < 4; j++)
        bf[j] = *reinterpret_cast<const short8x*>(&sB[wn + j * 16 + lr][kk]);
#pragma unroll
      for (int i = 0; i < 4; i++)
#pragma unroll
        for (int j = 0; j < 4; j++)
          acc[i][j] = __builtin_amdgcn_mfma_f32_16x16x32_bf16(a[i], bf[j], acc[i][j], 0, 0, 0);
    }
    if (k0 < 128) {   // feats slice passthrough -> fres (reads sA, no write hazard)
      for (int u = t; u < 1024; u += 256) {
        int row = u >> 3, seg = u & 7;
        *(uint4*)(fres + (m0 + row) * 128 + k0 + seg * 8) =
            *(const uint4*)&sA[row][seg * 8];
      }
    }
    __syncthreads();
  }
#pragma unroll
  for (int i = 0; i < 4; i++)
#pragma unroll
    for (int r = 0; r < 4; r++) {
      size_t row = m0 + wm + i * 16 + quad * 4 + r;
#pragma unroll
      for (int j = 0; j < 4; j++) {
        int c = wn + j * 16 + lr;
        m1[row * 128 + c] = f2us(geluf(acc[i][j][r] + b1[c]));
      }
    }
}

// ---------------- K2: depthwise 3x3 + GELU ([px][c] layout) ----------------
__global__ __launch_bounds__(256) void k_dw(
    const unsigned short* __restrict__ in, const float* __restrict__ wd,
    const float* __restrict__ bd, unsigned short* __restrict__ out) {
  __shared__ float w[Cc * 9];
  for (int i = threadIdx.x; i < Cc * 9; i += 256) w[i] = wd[i];
  __syncthreads();
  const int wave = threadIdx.x >> 6, lane = threadIdx.x & 63;
  const int pxg = blockIdx.x * 4 + wave;
  const int n = pxg >> 14, p = pxg & (Pc - 1);
  const int y = p >> 7, x = p & 127;
  const int c0 = 2 * lane;
  float a0 = bd[c0], a1 = bd[c0 + 1];
  const float* w0 = w + c0 * 9;
  const float* w1 = w + (c0 + 1) * 9;
#pragma unroll
  for (int dy = 0; dy < 3; ++dy) {
    int yy = y + dy - 1;
    if (yy < 0 || yy >= Hc) continue;
#pragma unroll
    for (int dx = 0; dx < 3; ++dx) {
      int xx = x + dx - 1;
      if (xx < 0 || xx >= Wc) continue;
      const unsigned short* row = in + ((size_t)(n * Pc + yy * Wc + xx)) * 128;
      ushort2 v = *(const ushort2*)(row + c0);
      a0 += w0[dy * 3 + dx] * us2f(v.x);
      a1 += w1[dy * 3 + dx] * us2f(v.y);
    }
  }
  ushort2 pk;
  pk.x = f2us(geluf(a0));
  pk.y = f2us(geluf(a1));
  *(ushort2*)(out + (size_t)pxg * 128 + c0) = pk;
}

// ---------------- K3: merge 1x1 conv 128->128 + bias + residual (MFMA) ----------------
__global__ __launch_bounds__(256) void k_merge2(
    const unsigned short* __restrict__ A, const unsigned short* __restrict__ w2b,
    const float* __restrict__ b2, const unsigned short* __restrict__ fres,
    unsigned short* __restrict__ X1) {
  __shared__ unsigned short sA[128][72];
  __shared__ unsigned short sB[128][72];
  const int t = threadIdx.x;
  const int wave = t >> 6, lane = t & 63, quad = lane >> 4, lr = lane & 15;
  const int wm = (wave >> 1) * 64, wn = (wave & 1) * 64;
  const size_t m0 = (size_t)blockIdx.x * 128;
  f32x4 acc[4][4];
#pragma unroll
  for (int i = 0; i < 4; i++)
#pragma unroll
    for (int j = 0; j < 4; j++) acc[i][j] = (f32x4){0.f, 0.f, 0.f, 0.f};

  for (int k0 = 0; k0 < 128; k0 += 64) {
    for (int u = t; u < 1024; u += 256) {
      int row = u >> 3, seg = u & 7;
      *(uint4*)&sA[row][seg * 8] =
          *(const uint4*)(A + (m0 + row) * 128 + k0 + seg * 8);
    }
    for (int u = t; u < 1024; u += 256) {
      int row = u >> 3, seg = u & 7;
      *(uint4*)&sB[row][seg * 8] =
          *(const uint4*)(w2b + (size_t)row * 128 + k0 + seg * 8);
    }
    __syncthreads();
#pragma unroll
    for (int ks = 0; ks < 2; ++ks) {
      const int kk = ks * 32 + quad * 8;
      short8x a[4], bf[4];
#pragma unroll
      for (int i = 0; i < 4; i++)
        a[i] = *reinterpret_cast<const short8x*>(&sA[wm + i * 16 + lr][kk]);
#pragma unroll
      for (int j = 0; j < 4; j++)
        bf[j] = *reinterpret_cast<const short8x*>(&sB[wn + j * 16 + lr][kk]);
#pragma unroll
      for (int i = 0; i < 4; i++)
#pragma unroll
        for (int j = 0; j < 4; j++)
          acc[i][j] = __builtin_amdgcn_mfma_f32_16x16x32_bf16(a[i], bf[j], acc[i][j], 0, 0, 0);
    }
    __syncthreads();
  }
#pragma unroll
  for (int i = 0; i < 4; i++)
#pragma unroll
    for (int r = 0; r < 4; r++) {
      size_t row = m0 + wm + i * 16 + quad * 4 + r;
#pragma unroll
      for (int j = 0; j < 4; j++) {
        int c = wn + j * 16 + lr;
        float v = acc[i][j][r] + b2[c] + us2f(fres[row * 128 + c]);
        X1[row * 128 + c] = f2us(v);
      }
    }
}

// ---------------- K4: fused bidirectional minGRU (MFMA + scans) ----------------
// Block: 16 spatial px x 6 views (96 A-rows) x 256 outs (interleaved h/g by 16).
__global__ __launch_bounds__(256) void k_gru(
    const unsigned short* __restrict__ X1, const unsigned short* __restrict__ Wg,
    const unsigned short* __restrict__ Wb, unsigned short* __restrict__ F2) {
  __shared__ unsigned short sA[96][72];
  __shared__ unsigned short sB[256][72];
  __shared__ unsigned short sH[96][136];
  const int t = threadIdx.x;
  const int wave = t >> 6, lane = t & 63, quad = lane >> 4, lr = lane & 15;
  const int blk = blockIdx.x;
  const int b = blk >> 10, p0 = (blk & 1023) << 4;
  f32x4 acc[6][4];
#pragma unroll
  for (int v = 0; v < 6; v++)
#pragma unroll
    for (int j = 0; j < 4; j++) acc[v][j] = (f32x4){0.f, 0.f, 0.f, 0.f};

  // ---- GEMM1: hg1 = X1 . Wg^T (Wg rows interleaved) ----
  for (int k0 = 0; k0 < 128; k0 += 64) {
    for (int u = t; u < 768; u += 256) {
      int r = u >> 3, seg = u & 7;
      int v = r >> 4, ps = r & 15;
      *(uint4*)&sA[r][seg * 8] =
          *(const uint4*)(X1 + ((size_t)((b * 6 + v) * Pc + p0 + ps)) * 128 + k0 + seg * 8);
    }
    for (int u = t; u < 2048; u += 256) {
      int rw = u >> 3, seg = u & 7;
      *(uint4*)&sB[rw][seg * 8] = *(const uint4*)(Wg + (size_t)rw * 128 + k0 + seg * 8);
    }
    __syncthreads();
#pragma unroll
    for (int ks = 0; ks < 2; ++ks) {
      const int kk = ks * 32 + quad * 8;
      short8x a[6], bf[4];
#pragma unroll
      for (int v = 0; v < 6; v++)
        a[v] = *reinterpret_cast<const short8x*>(&sA[v * 16 + lr][kk]);
#pragma unroll
      for (int j = 0; j < 4; j++)
        bf[j] = *reinterpret_cast<const short8x*>(&sB[wave * 64 + j * 16 + lr][kk]);
#pragma unroll
      for (int v = 0; v < 6; v++)
#pragma unroll
        for (int j = 0; j < 4; j++)
          acc[v][j] = __builtin_amdgcn_mfma_f32_16x16x32_bf16(a[v], bf[j], acc[v][j], 0, 0, 0);
    }
    __syncthreads();
  }
  // ---- scan1 (forward over v; flips over H cancel) -> sH [row][d] ----
#pragma unroll
  for (int q = 0; q < 2; q++)
#pragma unroll
    for (int r = 0; r < 4; r++) {
      float h = 0.f;
#pragma unroll
      for (int v = 0; v < 6; v++) {
        float hid = acc[v][2 * q][r], gat = acc[v][2 * q + 1][r];
        float z = sigm(gat);
        float ht = (hid >= 0.f) ? (hid + 0.5f) : sigm(hid);
        h = (1.f - z) * h + z * ht;
        sH[v * 16 + quad * 4 + r][wave * 32 + q * 16 + lr] = f2us(h);
      }
    }
  __syncthreads();

  // ---- GEMM2: hg2 = h1 . Wb^T ----
#pragma unroll
  for (int v = 0; v < 6; v++)
#pragma unroll
    for (int j = 0; j < 4; j++) acc[v][j] = (f32x4){0.f, 0.f, 0.f, 0.f};
  for (int k0 = 0; k0 < 128; k0 += 64) {
    for (int u = t; u < 2048; u += 256) {
      int rw = u >> 3, seg = u & 7;
      *(uint4*)&sB[rw][seg * 8] = *(const uint4*)(Wb + (size_t)rw * 128 + k0 + seg * 8);
    }
    __syncthreads();
#pragma unroll
    for (int ks = 0; ks < 2; ++ks) {
      const int kk = ks * 32 + quad * 8;
      short8x a[6], bf[4];
#pragma unroll
      for (int v = 0; v < 6; v++)
        a[v] = *reinterpret_cast<const short8x*>(&sH[v * 16 + lr][k0 + kk]);
#pragma unroll
      for (int j = 0; j < 4; j++)
        bf[j] = *reinterpret_cast<const short8x*>(&sB[wave * 64 + j * 16 + lr][kk]);
#pragma unroll
      for (int v = 0; v < 6; v++)
#pragma unroll
        for (int j = 0; j < 4; j++)
          acc[v][j] = __builtin_amdgcn_mfma_f32_16x16x32_bf16(a[v], bf[j], acc[v][j], 0, 0, 0);
    }
    __syncthreads();
  }
  // ---- scan2 -> F2 global ----
#pragma unroll
  for (int q = 0; q < 2; q++)
#pragma unroll
    for (int r = 0; r < 4; r++) {
      float h = 0.f;
#pragma unroll
      for (int v = 0; v < 6; v++) {
        float hid = acc[v][2 * q][r], gat = acc[v][2 * q + 1][r];
        float z = sigm(gat);
        float ht = (hid >= 0.f) ? (hid + 0.5f) : sigm(hid);
        h = (1.f - z) * h + z * ht;
        F2[((size_t)((b * 6 + v) * Pc + p0 + quad * 4 + r)) * 128 + wave * 32 + q * 16 + lr] =
            f2us(h);
      }
    }
}

// ---------------- K5: alpha = 3x3 conv 128->1 (wave per pixel) ----------------
__global__ __launch_bounds__(256) void k_alpha(
    const unsigned short* __restrict__ F, const float* __restrict__ wa,
    const float* __restrict__ ba, float* __restrict__ alpha) {
  __shared__ float w[Cc * 9];
  for (int i = threadIdx.x; i < Cc * 9; i += 256) w[i] = wa[i];
  __syncthreads();
  const int wave = threadIdx.x >> 6, lane = threadIdx.x & 63;
  const int pxg = blockIdx.x * 4 + wave;
  const int n = pxg >> 14, p = pxg & (Pc - 1);
  const int y = p >> 7, x = p & 127;
  const int c0 = 2 * lane;
  const float* w0 = w + c0 * 9;
  const float* w1 = w + (c0 + 1) * 9;
  float acc = 0.f;
#pragma unroll
  for (int dy = 0; dy < 3; ++dy) {
    int yy = y + dy - 1;
    if (yy < 0 || yy >= Hc) continue;
#pragma unroll
    for (int dx = 0; dx < 3; ++dx) {
      int xx = x + dx - 1;
      if (xx < 0 || xx >= Wc) continue;
      const unsigned short* row = F + ((size_t)(n * Pc + yy * Wc + xx)) * 128;
      ushort2 v = *(const ushort2*)(row + c0);
      acc += w0[dy * 3 + dx] * us2f(v.x) + w1[dy * 3 + dx] * us2f(v.y);
    }
  }
#pragma unroll
  for (int off = 32; off >= 1; off >>= 1) acc += __shfl_xor(acc, off);
  if (lane == 0) alpha[(size_t)n * Pc + p] = acc + ba[0];
}

// ---------------- K6: softmax over V + pool (wave per pixel) ----------------
__global__ __launch_bounds__(256) void k_pool(
    const unsigned short* __restrict__ F, const float* __restrict__ alpha,
    unsigned short* __restrict__ P2) {
  const int wave = threadIdx.x >> 6, lane = threadIdx.x & 63;
  const int px = blockIdx.x * 4 + wave;   // over B*P
  const int b = px >> 14, p = px & (Pc - 1);
  float av[Vc];
  float mx = -1e30f;
#pragma unroll
  for (int v = 0; v < Vc; ++v) {
    av[v] = alpha[(size_t)(b * Vc + v) * Pc + p];
    mx = fmaxf(mx, av[v]);
  }
  float s = 0.f;
#pragma unroll
  for (int v = 0; v < Vc; ++v) { av[v] = __expf(av[v] - mx); s += av[v]; }
  const float inv = 1.f / s;
  const int c0 = 2 * lane;
  float a0 = 0.f, a1 = 0.f;
#pragma unroll
  for (int v = 0; v < Vc; ++v) {
    ushort2 vv = *(const ushort2*)(F + ((size_t)((b * Vc + v) * Pc + p)) * 128 + c0);
    float sw = av[v] * inv;
    a0 += us2f(vv.x) * sw;
    a1 += us2f(vv.y) * sw;
  }
  ushort2 pk;
  pk.x = f2us(a0);
  pk.y = f2us(a1);
  *(ushort2*)(P2 + (size_t)px * 128 + c0) = pk;
}

// ---------------- K7: up 1x1 conv + pixel_shuffle(4) (MFMA) ----------------
__global__ __launch_bounds__(256) void k_up(
    const unsigned short* __restrict__ A, const unsigned short* __restrict__ wub,
    const float* __restrict__ bu, unsigned short* __restrict__ us_) {
  __shared__ unsigned short sA[128][72];
  __shared__ unsigned short sB[128][72];
  const int t = threadIdx.x;
  const int wave = t >> 6, lane = t & 63, quad = lane >> 4, lr = lane & 15;
  const int wm = (wave >> 1) * 64, wn = (wave & 1) * 64;
  const size_t m0 = (size_t)blockIdx.x * 128;
  f32x4 acc[4][4];
#pragma unroll
  for (int i = 0; i < 4; i++)
#pragma unroll
    for (int j = 0; j < 4; j++) acc[i][j] = (f32x4){0.f, 0.f, 0.f, 0.f};

  for (int k0 = 0; k0 < 128; k0 += 64) {
    for (int u = t; u < 1024; u += 256) {
      int row = u >> 3, seg = u & 7;
      *(uint4*)&sA[row][seg * 8] =
          *(const uint4*)(A + (m0 + row) * 128 + k0 + seg * 8);
    }
    for (int u = t; u < 1024; u += 256) {
      int row = u >> 3, seg = u & 7;
      *(uint4*)&sB[row][seg * 8] =
          *(const uint4*)(wub + (size_t)row * 128 + k0 + seg * 8);
    }
    __syncthreads();
#pragma unroll
    for (int ks = 0; ks < 2; ++ks) {
      const int kk = ks * 32 + quad * 8;
      short8x a[4], bf[4];
#pragma unroll
      for (int i = 0; i < 4; i++)
        a[i] = *reinterpret_cast<const short8x*>(&sA[wm + i * 16 + lr][kk]);
#pragma unroll
      for (int j = 0; j < 4; j++)
        bf[j] = *reinterpret_cast<const short8x*>(&sB[wn + j * 16 + lr][kk]);
#pragma unroll
      for (int i = 0; i < 4; i++)
#pragma unroll
        for (int j = 0; j < 4; j++)
          acc[i][j] = __builtin_amdgcn_mfma_f32_16x16x32_bf16(a[i], bf[j], acc[i][j], 0, 0, 0);
    }
    __syncthreads();
  }
#pragma unroll
  for (int i = 0; i < 4; i++)
#pragma unroll
    for (int r = 0; r < 4; r++) {
      size_t row = m0 + wm + i * 16 + quad * 4 + r;   // global pixel (b*P + p)
      int b = (int)(row >> 14), p = (int)(row & (Pc - 1));
      int y = p >> 7, x = p & 127;
#pragma unroll
      for (int j = 0; j < 4; j++) {
        int c = wn + j * 16 + lr;
        float v = acc[i][j][r] + bu[c];
        int co = c >> 4, r1 = (c >> 2) & 3, r2 = c & 3;
        us_[(((size_t)b * 8 + co) * 512 + (y * 4 + r1)) * 512 + (x * 4 + r2)] = f2us(v);
      }
    }
}

// ---------------- K8: 3x3 conv 8->3 on 512x512, fp32 output ----------------
__global__ __launch_bounds__(256) void k_outc(
    const unsigned short* __restrict__ us_, const float* __restrict__ wo,
    const float* __restrict__ bo, float* __restrict__ out) {
  __shared__ float w[3 * 8 * 9];
  for (int i = threadIdx.x; i < 216; i += 256) w[i] = wo[i];
  __syncthreads();
  int i = blockIdx.x;
  const int xh = i & 1; i >>= 1;
  const int Y = i & 511; i >>= 9;
  const int o = i % 3;
  const int b = i / 3;
  const int X = xh * 256 + threadIdx.x;
  float acc = bo[o];
  for (int ci = 0; ci < 8; ++ci) {
    const unsigned short* pl = us_ + ((size_t)b * 8 + ci) * 512 * 512;
    const float* wc = w + o * 72 + ci * 9;
#pragma unroll
    for (int dy = 0; dy < 3; ++dy) {
      int YY = Y + dy - 1;
      if (YY < 0 || YY >= 512) continue;
#pragma unroll
      for (int dx = 0; dx < 3; ++dx) {
        int XX = X + dx - 1;
        if (XX < 0 || XX >= 512) continue;
        acc += wc[dy * 3 + dx] * us2f(pl[(size_t)YY * 512 + XX]);
      }
    }
  }
  out[(((size_t)b * 3 + o) * 512 + Y) * 512 + X] = acc;
}

// ---------------- launcher ----------------
extern "C" void kernel_launch(void* const* d_in, const int* in_sizes, int n_in,
                              void* d_out, int out_size, void* d_ws, size_t ws_size,
                              hipStream_t stream) {
  const float* feats = (const float*)d_in[0];
  const float* prj = (const float*)d_in[1];
  const float* w1 = (const float*)d_in[2];
  const float* b1 = (const float*)d_in[3];
  const float* wd = (const float*)d_in[4];
  const float* bd = (const float*)d_in[5];
  const float* w2 = (const float*)d_in[6];
  const float* b2 = (const float*)d_in[7];
  const float* gw = (const float*)d_in[8];
  const float* gbw = (const float*)d_in[9];
  const float* wa = (const float*)d_in[10];
  const float* ba = (const float*)d_in[11];
  const float* wu = (const float*)d_in[12];
  const float* bu = (const float*)d_in[13];
  const float* wo = (const float*)d_in[14];
  const float* bo = (const float*)d_in[15];
  float* out = (float*)d_out;

  char* ws = (char*)d_ws;
  // big buffers (bf16 [px][128], 50,331,648 B each):
  unsigned short* buf0 = (unsigned short*)(ws + 0);            // m1, then X1
  unsigned short* buf1 = (unsigned short*)(ws + 50331648);     // dwout, then F2
  unsigned short* fres = (unsigned short*)(ws + 100663296);    // bf16 feats
  float* alpha = (float*)(ws + 150994944);                     // 786,432
  unsigned short* P2 = (unsigned short*)(ws + 151781376);      // 8,388,608
  unsigned short* ushuf = (unsigned short*)(ws + 160169984);   // 8,388,608
  unsigned short* wbf = (unsigned short*)(ws + 168558592);     // 262,144 (end ~168.8MB)

  const unsigned short* w1b = wbf;
  const unsigned short* w2b = wbf + 32768;
  const unsigned short* wub = wbf + 49152;
  const unsigned short* wgi = wbf + 65536;
  const unsigned short* wgbi = wbf + 98304;

  dim3 blk(256);
  k_prepw<<<dim3(512), blk, 0, stream>>>(w1, w2, wu, gw, gbw, wbf);
  k_merge1<<<dim3(NPX / 128), blk, 0, stream>>>(feats, prj, w1b, b1, buf0, fres);
  k_dw<<<dim3(NPX / 4), blk, 0, stream>>>(buf0, wd, bd, buf1);
  k_merge2<<<dim3(NPX / 128), blk, 0, stream>>>(buf1, w2b, b2, fres, buf0);
  k_gru<<<dim3(Bc * (Pc / 16)), blk, 0, stream>>>(buf0, wgi, wgbi, buf1);
  k_alpha<<<dim3(NPX / 4), blk, 0, stream>>>(buf1, wa, ba, alpha);
  k_pool<<<dim3(Bc * Pc / 4), blk, 0, stream>>>(buf1, alpha, P2);
  k_up<<<dim3(Bc * Pc / 128), blk, 0, stream>>>(P2, wub, bu, ushuf);
  k_outc<<<dim3(2 * 3 * 512 * 2), blk, 0, stream>>>(ushuf, wo, bo, out);

  (void)in_sizes; (void)n_in; (void)out_size; (void)ws_size;
}